// Round 3
// baseline (551.537 us; speedup 1.0000x reference)
//
#include <hip/hip_runtime.h>

// CustomAttention: out = softmax((x_t Wq^T + bq)(x_nt Wk^T + bk)^T) (x_nt Wv^T + bv)
// B=8, SQ=SKV=2048, D=1024. fp32 in/out, fp16 MFMA compute (fp32 accumulate).
//
// Round 3 changes vs round 2 (477 us):
//  - ONE fused projection dispatch (grid 1024x3): blockIdx.y selects Q/K/V.
//    3072 blocks -> ~3 full machine-fill rounds vs 3x(1 + 1/3-full tail).
//  - fp32->fp16 cast fused into projection A-staging (float4 loads + v_cvt +
//    ds_write_b128 into the same XOR-swizzled layout). Big cast dispatches gone.
//  - one weight-cast dispatch (grid 512x3) instead of 3.
//  Pipeline: cast_w -> proj_fused -> QK -> softmax -> PV  (5 dispatches).
//
// QK measured at 848 TF = m97-structure plateau (m103: ~874 TF); K-loop
// restructure past it is hand-asm territory (m131-m141 all neutral) - not tried.
//
// ws layout:
//  [0,64)    S16  (QK out)        [64,128)  P16 (softmax out)
//  [128,160) Q16  [160,192) K16   [192,224) Vt16
//  [224,230) W16: Wq|Wk|Wv fp16 contiguous

typedef _Float16 half8 __attribute__((ext_vector_type(8)));
typedef _Float16 half4v __attribute__((ext_vector_type(4)));
typedef float floatx4 __attribute__((ext_vector_type(4)));

__device__ __forceinline__ void async_copy16(const _Float16* g, _Float16* l) {
  __builtin_amdgcn_global_load_lds(
      (const __attribute__((address_space(1))) void*)g,
      (__attribute__((address_space(3))) void*)l,
      16, 0, 0);
}

// ---------------- weight cast fp32 -> fp16, all three in one dispatch ----------------
__global__ __launch_bounds__(256) void cast_w(const float* __restrict__ Wq,
                                              const float* __restrict__ Wk,
                                              const float* __restrict__ Wv,
                                              _Float16* __restrict__ dst) {
  const float* src = blockIdx.y == 0 ? Wq : (blockIdx.y == 1 ? Wk : Wv);
  const long base = (long)blockIdx.y * (1024l * 1024);
  long i = ((long)blockIdx.x * 256 + threadIdx.x) * 8;
  float4 a = *(const float4*)(src + i);
  float4 b = *(const float4*)(src + i + 4);
  half8 h;
  h[0] = (_Float16)a.x; h[1] = (_Float16)a.y; h[2] = (_Float16)a.z; h[3] = (_Float16)a.w;
  h[4] = (_Float16)b.x; h[5] = (_Float16)b.y; h[6] = (_Float16)b.z; h[7] = (_Float16)b.w;
  *(half8*)(dst + base + i) = h;
}

// ---------------- fused Q/K/V projection ----------------
// per block: C[128,128] tile of  A_f32[16384,1024] x W_f16[1024,1024]^T + bias
// blockIdx.y: 0 -> (tgt, Wq, bq) -> Q16 row-major
//             1 -> (ntg, Wk, bk) -> K16 row-major
//             2 -> (ntg, Wv, bv) -> Vt16[b][n][s] transposed
// A staged via VGPR (float4 x2 -> cvt -> ds_write_b128), B via global_load_lds.
// LDS layout XOR-swizzled (granule = logical ^ (row&7)) -> conflict-free b128 reads.
__global__ __launch_bounds__(256, 2) void proj_fused(
    const float* __restrict__ tgt, const float* __restrict__ ntg,
    const _Float16* __restrict__ Wall,
    const float* __restrict__ bq, const float* __restrict__ bk, const float* __restrict__ bv,
    _Float16* __restrict__ QK16, _Float16* __restrict__ Vt16) {
  constexpr int K = 1024, N = 1024;
  __shared__ __attribute__((aligned(16))) _Float16 As[128 * 64];  // 16 KB
  __shared__ __attribute__((aligned(16))) _Float16 Bs[128 * 64];  // 16 KB

  const int tid = threadIdx.x;
  const int lane = tid & 63;
  const int wave = tid >> 6;
  const int by = blockIdx.y;
  const int mblk = blockIdx.x >> 3;  // 0..127
  const int nblk = blockIdx.x & 7;   // 0..7

  const float* Ag = (by == 0 ? tgt : ntg) + (long)mblk * 128 * K;
  const _Float16* Bb = Wall + (long)by * (K * N) + (long)nblk * 128 * K;
  const float* bias = (by == 0) ? bq : (by == 1 ? bk : bv);

  const int wm = (wave & 1) * 64;
  const int wn = (wave >> 1) * 64;
  const int frow = lane & 15;
  const int fq = lane >> 4;
  const int fsw = frow & 7;

  floatx4 acc[4][4];
#pragma unroll
  for (int mt = 0; mt < 4; mt++)
#pragma unroll
    for (int nt = 0; nt < 4; nt++)
      acc[mt][nt] = (floatx4){0.f, 0.f, 0.f, 0.f};

  const int sr = tid >> 3;               // base row 0..31 (j adds 32j)
  const int gl = (tid & 7) ^ (sr & 7);   // logical granule (swizzle key j-invariant)
  const long gOff = (long)sr * K + gl * 8;  // element offset (floats for A, halfs for B)
  const int ldsOff = tid * 8;

  for (int k0 = 0; k0 < K; k0 += 64) {
    __syncthreads();
#pragma unroll
    for (int j = 0; j < 4; j++)
      async_copy16(Bb + gOff + (long)(32 * j) * K + k0, Bs + ldsOff + j * 2048);
    float4 u[4], w[4];
#pragma unroll
    for (int j = 0; j < 4; j++) {
      const float4* ap = (const float4*)(Ag + gOff + (long)(32 * j) * K + k0);
      u[j] = ap[0];
      w[j] = ap[1];
    }
#pragma unroll
    for (int j = 0; j < 4; j++) {
      half8 h;
      h[0] = (_Float16)u[j].x; h[1] = (_Float16)u[j].y;
      h[2] = (_Float16)u[j].z; h[3] = (_Float16)u[j].w;
      h[4] = (_Float16)w[j].x; h[5] = (_Float16)w[j].y;
      h[6] = (_Float16)w[j].z; h[7] = (_Float16)w[j].w;
      *(half8*)(As + ldsOff + j * 2048) = h;
    }
    __syncthreads();

#pragma unroll
    for (int h = 0; h < 2; h++) {
      half8 af[4], bf[4];
#pragma unroll
      for (int mt = 0; mt < 4; mt++)
        af[mt] = *(const half8*)(As + (wm + mt * 16 + frow) * 64 + ((h * 4 + fq) ^ fsw) * 8);
#pragma unroll
      for (int nt = 0; nt < 4; nt++)
        bf[nt] = *(const half8*)(Bs + (wn + nt * 16 + frow) * 64 + ((h * 4 + fq) ^ fsw) * 8);
#pragma unroll
      for (int mt = 0; mt < 4; mt++)
#pragma unroll
        for (int nt = 0; nt < 4; nt++)
          acc[mt][nt] = __builtin_amdgcn_mfma_f32_16x16x32_f16(af[mt], bf[nt], acc[mt][nt], 0, 0, 0);
    }
  }

  // acc[mt][nt][i] = C[wm+mt*16+fq*4+i][wn+nt*16+frow]
  if (by != 2) {
    _Float16* O = QK16 + (long)by * (16l * 1024 * 1024);
#pragma unroll
    for (int nt = 0; nt < 4; nt++) {
      const int n = nblk * 128 + wn + nt * 16 + frow;
      const float bvv = bias[n];
#pragma unroll
      for (int mt = 0; mt < 4; mt++) {
        const int rbase = mblk * 128 + wm + mt * 16 + fq * 4;
#pragma unroll
        for (int i = 0; i < 4; i++)
          O[(long)(rbase + i) * N + n] = (_Float16)(acc[mt][nt][i] + bvv);
      }
    }
  } else {
#pragma unroll
    for (int nt = 0; nt < 4; nt++) {
      const int n = nblk * 128 + wn + nt * 16 + frow;
      const float bvv = bias[n];
#pragma unroll
      for (int mt = 0; mt < 4; mt++) {
        const int rbase = mblk * 128 + wm + mt * 16 + fq * 4;
        const long bb = rbase >> 11;
        const int s = rbase & 2047;
        half4v hv;
#pragma unroll
        for (int i = 0; i < 4; i++) hv[i] = (_Float16)(acc[mt][nt][i] + bvv);
        *(half4v*)(Vt16 + bb * (2048l * 1024) + (long)n * 2048 + s) = hv;
      }
    }
  }
}

// ---------------- fp16 BT GEMM (attention): C[m,n] = sum_k A[m,k]*B[n,k] ----------------
// OMODE 2: fp32 out row-major per batch; OMODE 3: fp16 out row-major per batch
template <int OMODE>
__global__ __launch_bounds__(256, 2) void gemm_bt(const _Float16* __restrict__ A,
                                                  const _Float16* __restrict__ B,
                                                  void* __restrict__ out,
                                                  int K, int N,
                                                  long sA, long sB, long sO) {
  __shared__ __attribute__((aligned(16))) _Float16 As[128 * 64];
  __shared__ __attribute__((aligned(16))) _Float16 Bs[128 * 64];

  const int tid = threadIdx.x;
  const int lane = tid & 63;
  const int wave = tid >> 6;
  const long bz = blockIdx.z;

  const _Float16* Ab = A + bz * sA + (long)blockIdx.x * 128 * K;
  const _Float16* Bb = B + bz * sB + (long)blockIdx.y * 128 * K;

  const int wm = (wave & 1) * 64;
  const int wn = (wave >> 1) * 64;
  const int frow = lane & 15;
  const int fq = lane >> 4;
  const int fsw = frow & 7;

  floatx4 acc[4][4];
#pragma unroll
  for (int mt = 0; mt < 4; mt++)
#pragma unroll
    for (int nt = 0; nt < 4; nt++)
      acc[mt][nt] = (floatx4){0.f, 0.f, 0.f, 0.f};

  const int sr = tid >> 3;
  const int gl = (tid & 7) ^ (sr & 7);
  const long gOffBase = (long)sr * K + gl * 8;
  const int ldsOff = tid * 8;

  for (int k0 = 0; k0 < K; k0 += 64) {
    __syncthreads();
#pragma unroll
    for (int j = 0; j < 4; j++) {
      async_copy16(Ab + gOffBase + (long)(32 * j) * K + k0, As + ldsOff + j * 2048);
      async_copy16(Bb + gOffBase + (long)(32 * j) * K + k0, Bs + ldsOff + j * 2048);
    }
    __syncthreads();

#pragma unroll
    for (int h = 0; h < 2; h++) {
      half8 af[4], bf[4];
#pragma unroll
      for (int mt = 0; mt < 4; mt++)
        af[mt] = *(const half8*)(As + (wm + mt * 16 + frow) * 64 + ((h * 4 + fq) ^ fsw) * 8);
#pragma unroll
      for (int nt = 0; nt < 4; nt++)
        bf[nt] = *(const half8*)(Bs + (wn + nt * 16 + frow) * 64 + ((h * 4 + fq) ^ fsw) * 8);
#pragma unroll
      for (int mt = 0; mt < 4; mt++)
#pragma unroll
        for (int nt = 0; nt < 4; nt++)
          acc[mt][nt] = __builtin_amdgcn_mfma_f32_16x16x32_f16(af[mt], bf[nt], acc[mt][nt], 0, 0, 0);
    }
  }

  // acc[mt][nt][i] = C[wm+mt*16+fq*4+i][wn+nt*16+frow]
#pragma unroll
  for (int nt = 0; nt < 4; nt++) {
    const int n = blockIdx.y * 128 + wn + nt * 16 + frow;
#pragma unroll
    for (int mt = 0; mt < 4; mt++) {
      const int rbase = blockIdx.x * 128 + wm + mt * 16 + fq * 4;
#pragma unroll
      for (int i = 0; i < 4; i++) {
        if (OMODE == 2)
          ((float*)out + bz * sO)[(long)(rbase + i) * N + n] = acc[mt][nt][i];
        else
          ((_Float16*)out + bz * sO)[(long)(rbase + i) * N + n] = (_Float16)acc[mt][nt][i];
      }
    }
  }
}

// ---------------- row softmax: S fp16 [rows][2048] -> P fp16 ----------------
__global__ __launch_bounds__(256) void softmax_rows(const _Float16* __restrict__ S,
                                                    _Float16* __restrict__ P) {
  const long row = blockIdx.x;
  const _Float16* src = S + row * 2048;
  _Float16* dst = P + row * 2048;
  const int tid = threadIdx.x;

  half8 v = ((const half8*)src)[tid];
  float f[8];
#pragma unroll
  for (int i = 0; i < 8; i++) f[i] = (float)v[i];

  float m = fmaxf(fmaxf(fmaxf(f[0], f[1]), fmaxf(f[2], f[3])),
                  fmaxf(fmaxf(f[4], f[5]), fmaxf(f[6], f[7])));
#pragma unroll
  for (int o = 32; o > 0; o >>= 1) m = fmaxf(m, __shfl_xor(m, o, 64));
  __shared__ float redm[4];
  if ((tid & 63) == 0) redm[tid >> 6] = m;
  __syncthreads();
  m = fmaxf(fmaxf(redm[0], redm[1]), fmaxf(redm[2], redm[3]));

  float e[8], s = 0.f;
#pragma unroll
  for (int i = 0; i < 8; i++) { e[i] = __expf(f[i] - m); s += e[i]; }
#pragma unroll
  for (int o = 32; o > 0; o >>= 1) s += __shfl_xor(s, o, 64);
  __shared__ float reds[4];
  if ((tid & 63) == 0) reds[tid >> 6] = s;
  __syncthreads();
  s = (reds[0] + reds[1]) + (reds[2] + reds[3]);
  const float inv = 1.f / s;

  half8 h;
#pragma unroll
  for (int i = 0; i < 8; i++) h[i] = (_Float16)(e[i] * inv);
  ((half8*)dst)[tid] = h;
}

extern "C" void kernel_launch(void* const* d_in, const int* in_sizes, int n_in,
                              void* d_out, int out_size, void* d_ws, size_t ws_size,
                              hipStream_t stream) {
  const float* target = (const float*)d_in[0];
  const float* non_target = (const float*)d_in[1];
  const float* Wq = (const float*)d_in[2];
  const float* bq = (const float*)d_in[3];
  const float* Wk = (const float*)d_in[4];
  const float* bk = (const float*)d_in[5];
  const float* Wv = (const float*)d_in[6];
  const float* bv = (const float*)d_in[7];

  char* ws = (char*)d_ws;
  const size_t MB = 1ull << 20;
  _Float16* S16 = (_Float16*)(ws);              // 64 MiB
  _Float16* P16 = (_Float16*)(ws + 64 * MB);    // 64 MiB
  _Float16* Q16 = (_Float16*)(ws + 128 * MB);   // 32 MiB  (K16 directly after: QK16 contiguous)
  _Float16* Vt16 = (_Float16*)(ws + 192 * MB);  // 32 MiB
  _Float16* W16 = (_Float16*)(ws + 224 * MB);   // 6 MiB: Wq|Wk|Wv
  _Float16* K16 = Q16 + 16l * 1024 * 1024;

  // 1. weight casts (one dispatch)
  cast_w<<<dim3(512, 3), 256, 0, stream>>>(Wq, Wk, Wv, W16);

  // 2. fused projections (cast folded into A-staging)
  proj_fused<<<dim3(1024, 3), 256, 0, stream>>>(target, non_target, W16,
                                                bq, bk, bv, Q16, Vt16);

  // 3. scores: per batch [2048,2048] = Q_b x K_b^T (fp16 out)
  gemm_bt<3><<<dim3(16, 16, 8), 256, 0, stream>>>(Q16, K16, S16, 1024, 2048,
                                                  2048l * 1024, 2048l * 1024, 2048l * 2048);

  // 4. softmax rows -> P fp16
  softmax_rows<<<16384, 256, 0, stream>>>(S16, P16);

  // 5. out: per batch [2048,1024] = P_b x Vt_b^T (fp32 out to d_out)
  gemm_bt<2><<<dim3(16, 8, 8), 256, 0, stream>>>(P16, Vt16, (float*)d_out, 2048, 1024,
                                                 2048l * 2048, 1024l * 2048, 2048l * 1024);
}